// Round 5
// baseline (1762.608 us; speedup 1.0000x reference)
//
#include <hip/hip_runtime.h>

#define TNODES 32768
#define NEDGE  1048576
#define HD     128
#define NG     512     // 4*H gates
#define NB     64
#define SEQ    512
#define FCN    262144  // N_NODES^2

// ---------------------------------------------------------------- GCN: degree
__global__ __launch_bounds__(256) void k_deg(const int* __restrict__ ei,
                                             const float* __restrict__ ew,
                                             float* __restrict__ deg,
                                             int* __restrict__ cnt) {
    int e = blockIdx.x * 256 + threadIdx.x;
    int d = ei[NEDGE + e];          // dst row
    atomicAdd(&deg[d], ew[e]);
    atomicAdd(&cnt[d], 1);
}

__global__ __launch_bounds__(256) void k_dinv(float* __restrict__ deg) {
    int n = blockIdx.x * 256 + threadIdx.x;
    deg[n] = rsqrtf(deg[n] + 1.0f);   // self-loop w=1; deg>=1 always
}

// exclusive prefix scan of cnt[32768] -> offs[32769], single block
__global__ __launch_bounds__(1024) void k_scan(const int* __restrict__ cnt,
                                               int* __restrict__ offs) {
    __shared__ int sums[1024];
    int t = threadIdx.x;
    int base = t * 32;
    int local[32];
    int s = 0;
    #pragma unroll
    for (int j = 0; j < 32; ++j) { local[j] = s; s += cnt[base + j]; }
    sums[t] = s;
    __syncthreads();
    for (int off = 1; off < 1024; off <<= 1) {
        int v = sums[t];
        int u = (t >= off) ? sums[t - off] : 0;
        __syncthreads();
        sums[t] = v + u;
        __syncthreads();
    }
    int baseSum = (t == 0) ? 0 : sums[t - 1];
    #pragma unroll
    for (int j = 0; j < 32; ++j) offs[base + j] = baseSum + local[j];
    if (t == 1023) offs[TNODES] = sums[1023];
}

__global__ __launch_bounds__(256) void k_fill(const int* __restrict__ ei,
                                              const float* __restrict__ ew,
                                              const float* __restrict__ dinv,
                                              const int* __restrict__ offs,
                                              int* __restrict__ cursor,
                                              int* __restrict__ csrc,
                                              float* __restrict__ ca) {
    int e = blockIdx.x * 256 + threadIdx.x;
    int s = ei[e];
    int d = ei[NEDGE + e];
    int p = offs[d] + atomicAdd(&cursor[d], 1);
    csrc[p] = s;
    ca[p] = ew[e] * dinv[s];
}

// ------------------------------------------------- tiny transpose W_gcn -> Wt
__global__ __launch_bounds__(256) void k_transpose(const float* __restrict__ W,
                                                   float* __restrict__ Wt) {
    int t = blockIdx.x * 256 + threadIdx.x;   // 16384
    int c = t >> 7, k = t & 127;
    Wt[t] = W[k * HD + c];
}

// -------------------------------------------- generic C[R,G] = A[R,128]@Bt^T
// Bt is [G,128]; bias = bias1[g]+bias2[g] (either may be null). 64x64 tiles.
#define GS 140
__global__ __launch_bounds__(256) void k_gemm_bt(const float* __restrict__ A,
                                                 const float* __restrict__ Bt,
                                                 const float* __restrict__ b1,
                                                 const float* __restrict__ b2,
                                                 float* __restrict__ C, int G) {
    __shared__ __align__(16) float As[64 * GS];
    __shared__ __align__(16) float Bs[64 * GS];
    int r0 = blockIdx.x * 64;
    int g0 = blockIdx.y * 64;
    int tid = threadIdx.x;
    #pragma unroll
    for (int it = 0; it < 8; ++it) {
        int idx = tid + 256 * it;        // 0..2047
        int r = idx >> 5, c4 = idx & 31;
        float4 va = ((const float4*)(A + (size_t)(r0 + r) * HD))[c4];
        *((float4*)&As[r * GS + c4 * 4]) = va;
        float4 vb = ((const float4*)(Bt + (size_t)(g0 + r) * HD))[c4];
        *((float4*)&Bs[r * GS + c4 * 4]) = vb;
    }
    __syncthreads();
    int i = tid >> 4;    // 0..15 -> rows i + 16*mi
    int j = tid & 15;    // 0..15 -> cols j + 16*ni
    float acc[4][4];
    #pragma unroll
    for (int a = 0; a < 4; ++a)
        #pragma unroll
        for (int b = 0; b < 4; ++b) acc[a][b] = 0.f;
    #pragma unroll 8
    for (int k4 = 0; k4 < 32; ++k4) {
        float4 av[4], bv[4];
        #pragma unroll
        for (int mi = 0; mi < 4; ++mi)
            av[mi] = *((const float4*)&As[(i + 16 * mi) * GS + k4 * 4]);
        #pragma unroll
        for (int ni = 0; ni < 4; ++ni)
            bv[ni] = *((const float4*)&Bs[(j + 16 * ni) * GS + k4 * 4]);
        #pragma unroll
        for (int mi = 0; mi < 4; ++mi)
            #pragma unroll
            for (int ni = 0; ni < 4; ++ni)
                acc[mi][ni] += (av[mi].x * bv[ni].x + av[mi].y * bv[ni].y) +
                               (av[mi].z * bv[ni].z + av[mi].w * bv[ni].w);
    }
    #pragma unroll
    for (int mi = 0; mi < 4; ++mi)
        #pragma unroll
        for (int ni = 0; ni < 4; ++ni) {
            int g = g0 + j + 16 * ni;
            float bias = (b1 ? b1[g] : 0.f) + (b2 ? b2[g] : 0.f);
            C[(size_t)(r0 + i + 16 * mi) * G + g] = acc[mi][ni] + bias;
        }
}

// ------------------------------------------------------------ GCN aggregation
__global__ __launch_bounds__(128) void k_agg(const int* __restrict__ offs,
                                             const int* __restrict__ csrc,
                                             const float* __restrict__ ca,
                                             const float* __restrict__ xw,
                                             const float* __restrict__ dinv,
                                             const float* __restrict__ bg,
                                             float* __restrict__ hg) {
    int d = blockIdx.x;
    int t = threadIdx.x;
    int beg = offs[d], end = offs[d + 1];
    float acc = 0.f;
    int e = beg;
    for (; e + 3 < end; e += 4) {
        int s0 = csrc[e], s1 = csrc[e + 1], s2 = csrc[e + 2], s3 = csrc[e + 3];
        float a0 = ca[e], a1 = ca[e + 1], a2 = ca[e + 2], a3 = ca[e + 3];
        acc += a0 * xw[(size_t)s0 * HD + t];
        acc += a1 * xw[(size_t)s1 * HD + t];
        acc += a2 * xw[(size_t)s2 * HD + t];
        acc += a3 * xw[(size_t)s3 * HD + t];
    }
    for (; e < end; ++e) acc += ca[e] * xw[(size_t)csrc[e] * HD + t];
    float di = dinv[d];
    hg[(size_t)d * HD + t] = di * acc + di * di * xw[(size_t)d * HD + t] + bg[t];
}

// ----------------------------------------------------------------- LSTM scan
__device__ __forceinline__ float sigm(float x) { return 1.f / (1.f + __expf(-x)); }
__device__ __forceinline__ float tanh_s(float x) {
    float e = __expf(-2.f * fabsf(x));
    float t = (1.f - e) / (1.f + e);
    return copysignf(t, x);
}

// component select that folds to a direct member access under full unroll
#define COMP(v, j) ((j) == 0 ? (v).x : ((j) == 1 ? (v).y : ((j) == 2 ? (v).z : (v).w)))

// ROUND-4 RESTRUCTURE (resubmit; round-4 bench died to infra, no data):
// one barrier per step, no LDS h, no divergent phase-B.
//
// 512 threads. Thread (c = t>>7 in [0,4), i = t&127) holds gate rows
// {i, i+128, i+256, i+384} for k in [32c, 32c+32): 128 weight floats.
//
// Step skeleton (the invariant ~2030 cy/step across rounds 1-3 implicated the
// skeleton, not just the GEMV): previously 2 barriers + LDS h round-trip +
// pointwise confined to 128 of 512 threads. Now EVERY lane redundantly
// computes the pointwise for its own unit u = 32c + (lane&31) (pair-wave and
// hi-lane duplicates are free: 2 waves/SIMD x ~45 ops), keeps cst per-lane,
// and the next GEMV reads h via intra-wave readlane -- h never touches LDS.
// Gate partials are double-buffered (parity s&1) in LDS [0,4096) floats, so a
// SINGLE barrier per step orders write(buf[s^1]) vs read(buf[s^1]) next step.
// P-prefetch and Hout stores issue a full step (~1000+ cy) before the one
// vmcnt(0)-at-barrier drain -> HBM latency fully covered.
//
// Anti-sink discipline kept: weights staged through LDS [0,2048) floats =
// buf0, clobbered by the GEMV store every odd step -> per-step re-read of
// weights from LDS is illegal, remat from global impossible.
// LDS oversized (82432 B > 80 KiB): 1 block/CU, 64 chain-blocks on 64 CUs.
__global__ __launch_bounds__(512)
__attribute__((amdgpu_waves_per_eu(2, 2)))
void k_lstm(const float* __restrict__ P,
            const float* __restrict__ whh,
            float* __restrict__ Hout,
            float* __restrict__ lastOut) {
    __shared__ __align__(16) float lds[20608];   // 82432 B; buf0 [0,2048),
                                                 // buf1 [2048,4096) floats
    int b = blockIdx.x, t = threadIdx.x;
    int c = t >> 7;        // k-chunk (32 wide)
    int i = t & 127;       // gate-row base (rows i, i+128, i+256, i+384)
    int u = 32 * c + (t & 31);   // this lane's hidden unit (dup in hi-lanes)

    // ---- stage whh through the clobbered buf0 window: pass (g, h8) stages
    // rows [128g+16h8, 128g+16h8+16) x all k at lds[rl*128 + k].
    float4 w[4][8];        // [gate][q]: k = 32c + 4q .. +3
    for (int g = 0; g < 4; ++g) {
        for (int h8 = 0; h8 < 8; ++h8) {
            int rl = t >> 5;            // local row 0..15
            int kq = (t & 31) * 4;      // k 0,4,..,124
            float4 v = *(const float4*)(whh + (size_t)(128 * g + 16 * h8 + rl) * HD + kq);
            __syncthreads();            // prior pass's reads done before overwrite
            *(float4*)(lds + 4 * t) = v;    // == lds[rl*128 + kq]
            __syncthreads();
            if ((i >> 4) == h8) {
                int rr = i & 15;
                #pragma unroll
                for (int q = 0; q < 8; ++q)
                    w[g][q] = *(const float4*)(lds + rr * 128 + 32 * c + 4 * q);
            }
        }
    }
    __syncthreads();
    // gates(0) have no Whh*h term (h(-1)=0): zero buf0 = the s=0 partials.
    ((float4*)lds)[t] = float4{0.f, 0.f, 0.f, 0.f};

    float cst = 0.f;
    const float* Pb = P + (size_t)b * SEQ * NG;
    float pi = Pb[u], pf = Pb[128 + u], pg = Pb[256 + u], po = Pb[384 + u];
    __syncthreads();

    for (int s = 0; s < SEQ; ++s) {
        // prefetch P[s+1]: consumed next iteration; drains at this step's
        // single barrier -> full-step in-flight window.
        float pi2 = 0.f, pf2 = 0.f, pg2 = 0.f, po2 = 0.f;
        if (s + 1 < SEQ) {
            const float* Pn = Pb + (size_t)(s + 1) * NG;
            pi2 = Pn[u]; pf2 = Pn[128 + u]; pg2 = Pn[256 + u]; po2 = Pn[384 + u];
        }
        // ---- pointwise for unit u, in-lane (all 64 lanes; hi-lanes dup)
        const float4* buf = ((const float4*)lds) + (s & 1) * 512;
        float4 q0 = buf[u];
        float4 q1 = buf[128 + u];
        float4 q2 = buf[256 + u];
        float4 q3 = buf[384 + u];
        float gi = (q0.x + q1.x) + (q2.x + q3.x) + pi;
        float gf = (q0.y + q1.y) + (q2.y + q3.y) + pf;
        float gg = (q0.z + q1.z) + (q2.z + q3.z) + pg;
        float go = (q0.w + q1.w) + (q2.w + q3.w) + po;
        float i_ = sigm(gi), f_ = sigm(gf), g_ = tanh_s(gg), o_ = sigm(go);
        cst = fmaf(f_, cst, i_ * g_);
        float h = o_ * tanh_s(cst);
        if (Hout && (t & 96) == 0) Hout[((size_t)b * SEQ + s) * HD + u] = h;
        if (lastOut && s == SEQ - 1 && (t & 96) == 0) lastOut[b * HD + u] = h;
        pi = pi2; pf = pf2; pg = pg2; po = po2;

        // ---- GEMV: h[32c..32c+32) lives in lanes 0..31 of THIS wave
        if (s + 1 < SEQ) {
            float4 acc = {0.f, 0.f, 0.f, 0.f};
            #pragma unroll
            for (int k = 0; k < 32; ++k) {
                float hk = __int_as_float(__builtin_amdgcn_readlane(__float_as_int(h), k));
                acc.x = fmaf(COMP(w[0][k >> 2], k & 3), hk, acc.x);
                acc.y = fmaf(COMP(w[1][k >> 2], k & 3), hk, acc.y);
                acc.z = fmaf(COMP(w[2][k >> 2], k & 3), hk, acc.z);
                acc.w = fmaf(COMP(w[3][k >> 2], k & 3), hk, acc.w);
            }
            // partials for gates(s+1) -> buf[(s+1)&1]; clobbers buf0 on odd s
            ((float4*)lds)[((s + 1) & 1) * 512 + c * 128 + i] = acc;
        }
        __syncthreads();
    }
}

// ----------------------------------------------------------------------- FC
__global__ __launch_bounds__(256) void k_fc(const float* __restrict__ last,
                                            const float* __restrict__ fcw,
                                            const float* __restrict__ fcb,
                                            float* __restrict__ out) {
    __shared__ __align__(16) float l_sh[NB * HD];
    int tid = threadIdx.x;
    #pragma unroll
    for (int it = 0; it < 32; ++it) l_sh[tid + 256 * it] = last[tid + 256 * it];
    __syncthreads();
    int i = blockIdx.x * 256 + tid;
    const float4* wrow = (const float4*)(fcw + (size_t)i * HD);
    float acc[NB];
    #pragma unroll
    for (int b = 0; b < NB; ++b) acc[b] = 0.f;
    for (int k4 = 0; k4 < 32; ++k4) {
        float4 w4 = wrow[k4];
        #pragma unroll
        for (int b = 0; b < NB; ++b) {
            float4 l4 = ((const float4*)(l_sh + b * HD))[k4];
            acc[b] += (w4.x * l4.x + w4.y * l4.y) + (w4.z * l4.z + w4.w * l4.w);
        }
    }
    float bias = fcb[i];
    #pragma unroll
    for (int b = 0; b < NB; ++b) out[(size_t)b * FCN + i] = acc[b] + bias;
}

// -------------------------------------------------------------------- launch
extern "C" void kernel_launch(void* const* d_in, const int* in_sizes, int n_in,
                              void* d_out, int out_size, void* d_ws, size_t ws_size,
                              hipStream_t stream) {
    const float* x   = (const float*)d_in[0];
    const int*   ei  = (const int*)d_in[1];
    const float* ew  = (const float*)d_in[2];
    const float* Wg  = (const float*)d_in[4];
    const float* bg  = (const float*)d_in[5];
    const float* wih = (const float*)d_in[6];   // [2,512,128]
    const float* whh = (const float*)d_in[7];   // [2,512,128]
    const float* bih = (const float*)d_in[8];   // [2,512]
    const float* bhh = (const float*)d_in[9];
    const float* fcw = (const float*)d_in[10];  // [262144,128]
    const float* fcb = (const float*)d_in[11];
    float* out = (float*)d_out;

    float* ws = (float*)d_ws;
    float* deg    = ws;                         // 32768 (-> dinv in place)
    int*   cnt    = (int*)(ws + 32768);         // 32768
    int*   cursor = (int*)(ws + 65536);         // 32768
    int*   offs   = (int*)(ws + 98304);         // 32769
    int*   csrc   = (int*)(ws + 131136);        // 1048576
    float* ca     = ws + 1179712;               // 1048576
    float* Wt     = ws + 2228288;               // 16384
    float* xw     = ws + 2244672;               // 4194304
    float* hg     = ws + 6438976;               // 4194304
    float* H0     = ws + 10633280;              // 4194304
    float* lastb  = ws + 14827584;              // 8192
    float* P      = ws + 14835776;              // 16777216

    // zero deg, cnt, cursor in one shot
    hipMemsetAsync(d_ws, 0, 3 * 32768 * sizeof(float), stream);

    k_deg<<<NEDGE / 256, 256, 0, stream>>>(ei, ew, deg, cnt);
    k_dinv<<<TNODES / 256, 256, 0, stream>>>(deg);
    k_scan<<<1, 1024, 0, stream>>>(cnt, offs);
    k_fill<<<NEDGE / 256, 256, 0, stream>>>(ei, ew, deg, offs, cursor, csrc, ca);
    k_transpose<<<64, 256, 0, stream>>>(Wg, Wt);
    k_gemm_bt<<<dim3(TNODES / 64, HD / 64), 256, 0, stream>>>(x, Wt, nullptr, nullptr, xw, HD);
    k_agg<<<TNODES, 128, 0, stream>>>(offs, csrc, ca, xw, deg, bg, hg);

    // layer 0
    k_gemm_bt<<<dim3(TNODES / 64, NG / 64), 256, 0, stream>>>(hg, wih, bih, bhh, P, NG);
    k_lstm<<<NB, 512, 0, stream>>>(P, whh, H0, nullptr);
    // layer 1
    k_gemm_bt<<<dim3(TNODES / 64, NG / 64), 256, 0, stream>>>(H0, wih + 65536, bih + 512, bhh + 512, P, NG);
    k_lstm<<<NB, 512, 0, stream>>>(P, whh + 65536, nullptr, lastb);

    k_fc<<<FCN / 256, 256, 0, stream>>>(lastb, fcw, fcb, out);
}

// Round 6
// 1642.294 us; speedup vs baseline: 1.0733x; 1.0733x over previous
//
#include <hip/hip_runtime.h>

#define TNODES 32768
#define NEDGE  1048576
#define HD     128
#define NG     512     // 4*H gates
#define NB     64
#define SEQ    512
#define FCN    262144  // N_NODES^2

// ---------------------------------------------------------------- GCN: degree
__global__ __launch_bounds__(256) void k_deg(const int* __restrict__ ei,
                                             const float* __restrict__ ew,
                                             float* __restrict__ deg,
                                             int* __restrict__ cnt) {
    int e = blockIdx.x * 256 + threadIdx.x;
    int d = ei[NEDGE + e];          // dst row
    atomicAdd(&deg[d], ew[e]);
    atomicAdd(&cnt[d], 1);
}

__global__ __launch_bounds__(256) void k_dinv(float* __restrict__ deg) {
    int n = blockIdx.x * 256 + threadIdx.x;
    deg[n] = rsqrtf(deg[n] + 1.0f);   // self-loop w=1; deg>=1 always
}

// exclusive prefix scan of cnt[32768] -> offs[32769], single block
__global__ __launch_bounds__(1024) void k_scan(const int* __restrict__ cnt,
                                               int* __restrict__ offs) {
    __shared__ int sums[1024];
    int t = threadIdx.x;
    int base = t * 32;
    int local[32];
    int s = 0;
    #pragma unroll
    for (int j = 0; j < 32; ++j) { local[j] = s; s += cnt[base + j]; }
    sums[t] = s;
    __syncthreads();
    for (int off = 1; off < 1024; off <<= 1) {
        int v = sums[t];
        int u = (t >= off) ? sums[t - off] : 0;
        __syncthreads();
        sums[t] = v + u;
        __syncthreads();
    }
    int baseSum = (t == 0) ? 0 : sums[t - 1];
    #pragma unroll
    for (int j = 0; j < 32; ++j) offs[base + j] = baseSum + local[j];
    if (t == 1023) offs[TNODES] = sums[1023];
}

__global__ __launch_bounds__(256) void k_fill(const int* __restrict__ ei,
                                              const float* __restrict__ ew,
                                              const float* __restrict__ dinv,
                                              const int* __restrict__ offs,
                                              int* __restrict__ cursor,
                                              int* __restrict__ csrc,
                                              float* __restrict__ ca) {
    int e = blockIdx.x * 256 + threadIdx.x;
    int s = ei[e];
    int d = ei[NEDGE + e];
    int p = offs[d] + atomicAdd(&cursor[d], 1);
    csrc[p] = s;
    ca[p] = ew[e] * dinv[s];
}

// ------------------------------------------------- tiny transpose W_gcn -> Wt
__global__ __launch_bounds__(256) void k_transpose(const float* __restrict__ W,
                                                   float* __restrict__ Wt) {
    int t = blockIdx.x * 256 + threadIdx.x;   // 16384
    int c = t >> 7, k = t & 127;
    Wt[t] = W[k * HD + c];
}

// -------------------------------------------- generic C[R,G] = A[R,128]@Bt^T
// Bt is [G,128]; bias = bias1[g]+bias2[g] (either may be null). 64x64 tiles.
#define GS 140
__global__ __launch_bounds__(256) void k_gemm_bt(const float* __restrict__ A,
                                                 const float* __restrict__ Bt,
                                                 const float* __restrict__ b1,
                                                 const float* __restrict__ b2,
                                                 float* __restrict__ C, int G) {
    __shared__ __align__(16) float As[64 * GS];
    __shared__ __align__(16) float Bs[64 * GS];
    int r0 = blockIdx.x * 64;
    int g0 = blockIdx.y * 64;
    int tid = threadIdx.x;
    #pragma unroll
    for (int it = 0; it < 8; ++it) {
        int idx = tid + 256 * it;        // 0..2047
        int r = idx >> 5, c4 = idx & 31;
        float4 va = ((const float4*)(A + (size_t)(r0 + r) * HD))[c4];
        *((float4*)&As[r * GS + c4 * 4]) = va;
        float4 vb = ((const float4*)(Bt + (size_t)(g0 + r) * HD))[c4];
        *((float4*)&Bs[r * GS + c4 * 4]) = vb;
    }
    __syncthreads();
    int i = tid >> 4;    // 0..15 -> rows i + 16*mi
    int j = tid & 15;    // 0..15 -> cols j + 16*ni
    float acc[4][4];
    #pragma unroll
    for (int a = 0; a < 4; ++a)
        #pragma unroll
        for (int b = 0; b < 4; ++b) acc[a][b] = 0.f;
    #pragma unroll 8
    for (int k4 = 0; k4 < 32; ++k4) {
        float4 av[4], bv[4];
        #pragma unroll
        for (int mi = 0; mi < 4; ++mi)
            av[mi] = *((const float4*)&As[(i + 16 * mi) * GS + k4 * 4]);
        #pragma unroll
        for (int ni = 0; ni < 4; ++ni)
            bv[ni] = *((const float4*)&Bs[(j + 16 * ni) * GS + k4 * 4]);
        #pragma unroll
        for (int mi = 0; mi < 4; ++mi)
            #pragma unroll
            for (int ni = 0; ni < 4; ++ni)
                acc[mi][ni] += (av[mi].x * bv[ni].x + av[mi].y * bv[ni].y) +
                               (av[mi].z * bv[ni].z + av[mi].w * bv[ni].w);
    }
    #pragma unroll
    for (int mi = 0; mi < 4; ++mi)
        #pragma unroll
        for (int ni = 0; ni < 4; ++ni) {
            int g = g0 + j + 16 * ni;
            float bias = (b1 ? b1[g] : 0.f) + (b2 ? b2[g] : 0.f);
            C[(size_t)(r0 + i + 16 * mi) * G + g] = acc[mi][ni] + bias;
        }
}

// ------------------------------------------------------------ GCN aggregation
__global__ __launch_bounds__(128) void k_agg(const int* __restrict__ offs,
                                             const int* __restrict__ csrc,
                                             const float* __restrict__ ca,
                                             const float* __restrict__ xw,
                                             const float* __restrict__ dinv,
                                             const float* __restrict__ bg,
                                             float* __restrict__ hg) {
    int d = blockIdx.x;
    int t = threadIdx.x;
    int beg = offs[d], end = offs[d + 1];
    float acc = 0.f;
    int e = beg;
    for (; e + 3 < end; e += 4) {
        int s0 = csrc[e], s1 = csrc[e + 1], s2 = csrc[e + 2], s3 = csrc[e + 3];
        float a0 = ca[e], a1 = ca[e + 1], a2 = ca[e + 2], a3 = ca[e + 3];
        acc += a0 * xw[(size_t)s0 * HD + t];
        acc += a1 * xw[(size_t)s1 * HD + t];
        acc += a2 * xw[(size_t)s2 * HD + t];
        acc += a3 * xw[(size_t)s3 * HD + t];
    }
    for (; e < end; ++e) acc += ca[e] * xw[(size_t)csrc[e] * HD + t];
    float di = dinv[d];
    hg[(size_t)d * HD + t] = di * acc + di * di * xw[(size_t)d * HD + t] + bg[t];
}

// ----------------------------------------------------------------- LSTM scan
__device__ __forceinline__ float sigm(float x) { return 1.f / (1.f + __expf(-x)); }
__device__ __forceinline__ float tanh_s(float x) {
    float e = __expf(-2.f * fabsf(x));
    float t = (1.f - e) / (1.f + e);
    return copysignf(t, x);
}

typedef float f2 __attribute__((ext_vector_type(2)));

// ROUND-6: round-3 skeleton (2 barriers, phase-B on t<128, best measured) with
// the GEMV core rebuilt:
//  (1) Weights loaded DIRECTLY from global as float2 pairs and pinned into
//      arch VGPRs with per-value asm volatile("" : "+v"(w)). The pin redefines
//      each value as an asm output: remat/sink is illegal, and the "v"
//      constraint cannot be satisfied by an AGPR. This targets the measured
//      parasite: rounds 1/3/5 all showed VGPR_Count (100/104) BELOW the 128
//      live weight floats -> allocator parked weights in AGPRs and paid
//      v_accvgpr_read per FMA (~500 cy/step). The LDS staging dance is gone.
//  (2) v_pk_fma_f32: 64 packed FMAs replace 128 scalar FMAs
//      (__builtin_elementwise_fma on 2-wide vectors lowers to pk_fma on
//      gfx90a+). h comes as wave-uniform ds_read pairs from h_sh (hardware
//      broadcast, no bank conflicts) -> the 32 readlanes are gone too.
// Per-wave GEMV issue: 8 ds_read_b128 + 64 pk_fma + eps ~= 350 cy/SIMD at
// 2 waves/SIMD (was 640 ideal + ~500 churn).
//
// 512 threads. Thread (c = t>>7 in [0,4), i = t&127) holds gate rows
// {i, i+128, i+256, i+384} for k in [32c, 32c+32) = 16 f2 pairs x 4 gates.
// LDS oversized (82432 B > 80 KiB): 1 block/CU, 64 chain-blocks on 64 CUs.
__global__ __launch_bounds__(512)
__attribute__((amdgpu_waves_per_eu(2, 2)))
void k_lstm(const float* __restrict__ P,
            const float* __restrict__ whh,
            float* __restrict__ Hout,
            float* __restrict__ lastOut) {
    __shared__ __align__(16) float lds[20608];   // 82432 B; partials [0,2048),
                                                 // h at 2048
    float* h_sh = lds + 2048;                    // [128]
    int b = blockIdx.x, t = threadIdx.x;
    int c = t >> 7;        // k-chunk (32 wide)
    int i = t & 127;       // hidden unit (this thread's 4 gate rows)

    // ---- load weights straight from global (one-time; whh is 256KB, L2/L3
    // resident). 8 float4 loads per gate row -> 16 f2 pairs.
    f2 w2[4][16];          // [gate][pair]: k = 32c + 2p, 2p+1
    #pragma unroll
    for (int g = 0; g < 4; ++g) {
        const float* wr = whh + (size_t)(i + 128 * g) * HD + 32 * c;
        #pragma unroll
        for (int q = 0; q < 8; ++q) {
            float4 v = *(const float4*)(wr + 4 * q);
            w2[g][2 * q]     = f2{v.x, v.y};
            w2[g][2 * q + 1] = f2{v.z, v.w};
        }
    }
    // ---- pin: asm output redefinition -> no remat, no sink, arch VGPR only.
    #pragma unroll
    for (int g = 0; g < 4; ++g)
        #pragma unroll
        for (int p = 0; p < 16; ++p)
            asm volatile("" : "+v"(w2[g][p]));

    if (t < HD) h_sh[t] = 0.f;
    float cst = 0.f;
    const float* Pb = P + (size_t)b * SEQ * NG;
    float pi = 0.f, pf = 0.f, pg = 0.f, po = 0.f;
    if (t < HD) { pi = Pb[t]; pf = Pb[128 + t]; pg = Pb[256 + t]; po = Pb[384 + t]; }
    __syncthreads();

    for (int s = 0; s < SEQ; ++s) {
        // prefetch next step's gate pre-activations: full GEMV+phaseB window
        // to cover L3/HBM latency before the barrier drain.
        float pi2 = 0.f, pf2 = 0.f, pg2 = 0.f, po2 = 0.f;
        if (t < HD && s + 1 < SEQ) {
            const float* Pn = Pb + (size_t)(s + 1) * NG;
            pi2 = Pn[t]; pf2 = Pn[128 + t]; pg2 = Pn[256 + t]; po2 = Pn[384 + t];
        }

        // ---- GEMV: h pairs via wave-uniform LDS reads (HW broadcast).
        // Two accumulators per gate (even/odd pairs) for ILP; pk_fma lowering.
        f2 a0 = {0.f, 0.f}, a1 = {0.f, 0.f}, a2 = {0.f, 0.f}, a3 = {0.f, 0.f};
        f2 e0 = {0.f, 0.f}, e1 = {0.f, 0.f}, e2 = {0.f, 0.f}, e3 = {0.f, 0.f};
        const float* hb = h_sh + 32 * c;
        #pragma unroll
        for (int p = 0; p < 16; p += 2) {
            f2 h2a = *(const f2*)(hb + 2 * p);
            f2 h2b = *(const f2*)(hb + 2 * p + 2);
            a0 = __builtin_elementwise_fma(w2[0][p], h2a, a0);
            a1 = __builtin_elementwise_fma(w2[1][p], h2a, a1);
            a2 = __builtin_elementwise_fma(w2[2][p], h2a, a2);
            a3 = __builtin_elementwise_fma(w2[3][p], h2a, a3);
            e0 = __builtin_elementwise_fma(w2[0][p + 1], h2b, e0);
            e1 = __builtin_elementwise_fma(w2[1][p + 1], h2b, e1);
            e2 = __builtin_elementwise_fma(w2[2][p + 1], h2b, e2);
            e3 = __builtin_elementwise_fma(w2[3][p + 1], h2b, e3);
        }
        f2 g0 = a0 + e0, g1 = a1 + e1, g2 = a2 + e2, g3 = a3 + e3;
        ((float4*)lds)[c * 128 + i] =
            float4{g0[0] + g0[1], g1[0] + g1[1], g2[0] + g2[1], g3[0] + g3[1]};
        __syncthreads();

        if (t < HD) {
            float4 s0 = ((const float4*)lds)[t];
            float4 s1 = ((const float4*)lds)[128 + t];
            float4 s2 = ((const float4*)lds)[256 + t];
            float4 s3 = ((const float4*)lds)[384 + t];
            float gi = (s0.x + s1.x) + (s2.x + s3.x) + pi;
            float gf = (s0.y + s1.y) + (s2.y + s3.y) + pf;
            float gg = (s0.z + s1.z) + (s2.z + s3.z) + pg;
            float go = (s0.w + s1.w) + (s2.w + s3.w) + po;
            float i_ = sigm(gi), f_ = sigm(gf), g_ = tanh_s(gg), o_ = sigm(go);
            cst = fmaf(f_, cst, i_ * g_);
            float h = o_ * tanh_s(cst);
            h_sh[t] = h;
            if (Hout) Hout[((size_t)b * SEQ + s) * HD + t] = h;
            if (lastOut && s == SEQ - 1) lastOut[b * HD + t] = h;
        }
        pi = pi2; pf = pf2; pg = pg2; po = po2;
        __syncthreads();
    }
}

// ----------------------------------------------------------------------- FC
__global__ __launch_bounds__(256) void k_fc(const float* __restrict__ last,
                                            const float* __restrict__ fcw,
                                            const float* __restrict__ fcb,
                                            float* __restrict__ out) {
    __shared__ __align__(16) float l_sh[NB * HD];
    int tid = threadIdx.x;
    #pragma unroll
    for (int it = 0; it < 32; ++it) l_sh[tid + 256 * it] = last[tid + 256 * it];
    __syncthreads();
    int i = blockIdx.x * 256 + tid;
    const float4* wrow = (const float4*)(fcw + (size_t)i * HD);
    float acc[NB];
    #pragma unroll
    for (int b = 0; b < NB; ++b) acc[b] = 0.f;
    for (int k4 = 0; k4 < 32; ++k4) {
        float4 w4 = wrow[k4];
        #pragma unroll
        for (int b = 0; b < NB; ++b) {
            float4 l4 = ((const float4*)(l_sh + b * HD))[k4];
            acc[b] += (w4.x * l4.x + w4.y * l4.y) + (w4.z * l4.z + w4.w * l4.w);
        }
    }
    float bias = fcb[i];
    #pragma unroll
    for (int b = 0; b < NB; ++b) out[(size_t)b * FCN + i] = acc[b] + bias;
}

// -------------------------------------------------------------------- launch
extern "C" void kernel_launch(void* const* d_in, const int* in_sizes, int n_in,
                              void* d_out, int out_size, void* d_ws, size_t ws_size,
                              hipStream_t stream) {
    const float* x   = (const float*)d_in[0];
    const int*   ei  = (const int*)d_in[1];
    const float* ew  = (const float*)d_in[2];
    const float* Wg  = (const float*)d_in[4];
    const float* bg  = (const float*)d_in[5];
    const float* wih = (const float*)d_in[6];   // [2,512,128]
    const float* whh = (const float*)d_in[7];   // [2,512,128]
    const float* bih = (const float*)d_in[8];   // [2,512]
    const float* bhh = (const float*)d_in[9];
    const float* fcw = (const float*)d_in[10];  // [262144,128]
    const float* fcb = (const float*)d_in[11];
    float* out = (float*)d_out;

    float* ws = (float*)d_ws;
    float* deg    = ws;                         // 32768 (-> dinv in place)
    int*   cnt    = (int*)(ws + 32768);         // 32768
    int*   cursor = (int*)(ws + 65536);         // 32768
    int*   offs   = (int*)(ws + 98304);         // 32769
    int*   csrc   = (int*)(ws + 131136);        // 1048576
    float* ca     = ws + 1179712;               // 1048576
    float* Wt     = ws + 2228288;               // 16384
    float* xw     = ws + 2244672;               // 4194304
    float* hg     = ws + 6438976;               // 4194304
    float* H0     = ws + 10633280;              // 4194304
    float* lastb  = ws + 14827584;              // 8192
    float* P      = ws + 14835776;              // 16777216

    // zero deg, cnt, cursor in one shot
    hipMemsetAsync(d_ws, 0, 3 * 32768 * sizeof(float), stream);

    k_deg<<<NEDGE / 256, 256, 0, stream>>>(ei, ew, deg, cnt);
    k_dinv<<<TNODES / 256, 256, 0, stream>>>(deg);
    k_scan<<<1, 1024, 0, stream>>>(cnt, offs);
    k_fill<<<NEDGE / 256, 256, 0, stream>>>(ei, ew, deg, offs, cursor, csrc, ca);
    k_transpose<<<64, 256, 0, stream>>>(Wg, Wt);
    k_gemm_bt<<<dim3(TNODES / 64, HD / 64), 256, 0, stream>>>(x, Wt, nullptr, nullptr, xw, HD);
    k_agg<<<TNODES, 128, 0, stream>>>(offs, csrc, ca, xw, deg, bg, hg);

    // layer 0
    k_gemm_bt<<<dim3(TNODES / 64, NG / 64), 256, 0, stream>>>(hg, wih, bih, bhh, P, NG);
    k_lstm<<<NB, 512, 0, stream>>>(P, whh, H0, nullptr);
    // layer 1
    k_gemm_bt<<<dim3(TNODES / 64, NG / 64), 256, 0, stream>>>(H0, wih + 65536, bih + 512, bhh + 512, P, NG);
    k_lstm<<<NB, 512, 0, stream>>>(P, whh + 65536, nullptr, lastb);

    k_fc<<<FCN / 256, 256, 0, stream>>>(lastb, fcw, fcb, out);
}